// Round 10
// baseline (16002.426 us; speedup 1.0000x reference)
//
#include <hip/hip_runtime.h>
#include <math.h>
#include <float.h>

#define B_ 128
#define T_ 80
#define D_ 4096
#define H_ 1024
#define V_ 6000
#define VP 6016          // V padded to 128
#define S_ 10
#define G3 (3*H_)
#define KSPLIT 4         // decoder standalone GEMMs only
#define NBLK 256         // persistent-kernel grid
#define BAR_MASTER 320
#define BAR_GEN    336

typedef unsigned short ushort_t;
typedef unsigned long long ull_t;
typedef __attribute__((ext_vector_type(8))) short s16x8;
typedef __attribute__((ext_vector_type(4))) float fx4;

// ---------------- static device scratch ----------------
__device__ float    g_gi[(size_t)B_*T_*G3];        // precomputed x@Wih^T+bih, all t
__device__ ushort_t g_Ah[(size_t)B_*T_*D_];
__device__ ushort_t g_Al[(size_t)B_*T_*D_];
__device__ ushort_t g_Bh[(size_t)G3*D_];
__device__ ushort_t g_Bl[(size_t)G3*D_];
__device__ ushort_t g_Whh_h[G3*H_],  g_Whh_l[G3*H_];
__device__ ushort_t g_dWih_h[G3*H_], g_dWih_l[G3*H_];
__device__ ushort_t g_dWhh_h[G3*H_], g_dWhh_l[G3*H_];
__device__ ushort_t g_l1h[H_*2*H_],  g_l1l[H_*2*H_];
__device__ ushort_t g_l2h[(size_t)VP*H_], g_l2l[(size_t)VP*H_];
// decoder split-K partials (standalone kernels)
__device__ float g_ghp [KSPLIT*B_*G3];
__device__ float g_gi2p[KSPLIT*B_*G3];
__device__ float g_gh2p[KSPLIT*B_*G3];
__device__ float g_up  [KSPLIT*B_*H_];
// encoder full-K outputs (read-once, sc1 both sides)
__device__ float g_ghs [B_*G3];
__device__ float g_gh2s[B_*G3];
__device__ float g_gi2s[B_*G3];
__device__ float g_us  [B_*H_];
// fp32 states (same-thread access only inside enc_persist)
__device__ float g_eh[B_*H_];
__device__ float g_dh[B_*H_];
// per-step activation RINGS (sc1-written, PLAIN-read: unique addr per step)
__device__ ushort_t g_ehh_r[(size_t)T_*B_*H_],     g_ehl_r[(size_t)T_*B_*H_];
__device__ ushort_t g_dhh_r[(size_t)(T_+1)*B_*H_], g_dhl_r[(size_t)(T_+1)*B_*H_];
__device__ ushort_t g_uh_r[(size_t)T_*B_*H_],      g_ul_r[(size_t)T_*B_*H_];
// decoder scratch
__device__ ushort_t g_uh[B_*H_],  g_ul[B_*H_];
__device__ ushort_t g_cath[B_*2*H_], g_catl[B_*2*H_];
__device__ float g_logitsp[2*B_*VP];
__device__ int   g_word[B_];
__device__ int   g_bar[512];

// ---------------- coherent (sc1) helpers: relaxed agent atomics ----------------
__device__ __forceinline__ ull_t ald64(const void* p) {
    return __hip_atomic_load((const ull_t*)p, __ATOMIC_RELAXED, __HIP_MEMORY_SCOPE_AGENT);
}
__device__ __forceinline__ void ast32(void* p, unsigned v) {
    __hip_atomic_store((unsigned*)p, v, __ATOMIC_RELAXED, __HIP_MEMORY_SCOPE_AGENT);
}
__device__ __forceinline__ void astf(float* p, float v) {
    ast32(p, __float_as_uint(v));
}
__device__ __forceinline__ float2 u2f2(ull_t v) {
    union { ull_t u; float2 f; } x; x.u = v; return x.f;
}

// ---------------- fp32 -> bf16 hi/lo split (RNE) ----------------
__device__ __forceinline__ void split1(float x, ushort_t& hi, ushort_t& lo) {
    unsigned u = __float_as_uint(x);
    unsigned rh = u + 0x7FFF + ((u >> 16) & 1);
    hi = (ushort_t)(rh >> 16);
    float fhi = __uint_as_float((unsigned)hi << 16);
    float d = x - fhi;
    unsigned u2 = __float_as_uint(d);
    unsigned rl = u2 + 0x7FFF + ((u2 >> 16) & 1);
    lo = (ushort_t)(rl >> 16);
}

__global__ __launch_bounds__(256) void split_bf16(
    const float* __restrict__ x, ushort_t* __restrict__ hi,
    ushort_t* __restrict__ lo, int n4)
{
    int i = blockIdx.x * 256 + threadIdx.x;
    if (i >= n4) return;
    float4 v = ((const float4*)x)[i];
    ushort_t h0,h1,h2,h3,l0,l1,l2,l3;
    split1(v.x,h0,l0); split1(v.y,h1,l1); split1(v.z,h2,l2); split1(v.w,h3,l3);
    ushort_t* hp = hi + (size_t)i*4;  hp[0]=h0; hp[1]=h1; hp[2]=h2; hp[3]=h3;
    ushort_t* lp = lo + (size_t)i*4;  lp[0]=l0; lp[1]=l1; lp[2]=l2; lp[3]=l3;
}

// ---------------- async global->LDS 16B ----------------
__device__ __forceinline__ void gld16(const ushort_t* g, void* l) {
    __builtin_amdgcn_global_load_lds(
        (const __attribute__((address_space(1))) void*)(const void*)g,
        (__attribute__((address_space(3))) void*)l, 16, 0, 0);
}

// ---------------- GRU elementwise core ----------------
__device__ __forceinline__ float gru_elem(float ir,float iz,float inn,
                                          float hr,float hz,float hn,float hprev){
    const float r = 1.f/(1.f+expf(-(ir+hr)));
    const float z = 1.f/(1.f+expf(-(iz+hz)));
    const float n = tanhf(inn + r*hn);
    return (1.f-z)*n + z*hprev;
}

// ---------------- standalone bf16x3 MFMA GEMM (precompute + decoder) ----------------
__global__ __launch_bounds__(256) void gemm_x3(
    const ushort_t* __restrict__ Ah, const ushort_t* __restrict__ Al, int lda,
    const ushort_t* __restrict__ Bh, const ushort_t* __restrict__ Bl, int ldw,
    const float* __restrict__ bias,
    float* __restrict__ C,
    int M, int N, int K, int kchunks,
    const ushort_t* __restrict__ A2h, const ushort_t* __restrict__ A2l,
    const ushort_t* __restrict__ B2h, const ushort_t* __restrict__ B2l,
    float* __restrict__ C2)
{
    int z = blockIdx.z;
    int kc = z;
    if (z >= kchunks) { kc = z - kchunks; Ah=A2h; Al=A2l; Bh=B2h; Bl=B2l; C=C2; }

    __shared__ ushort_t sAh[2][128*32], sAl[2][128*32];
    __shared__ ushort_t sBh[2][128*32], sBl[2][128*32];

    const int tid  = threadIdx.x;
    const int bm   = blockIdx.y * 128, bn = blockIdx.x * 128;
    const int wave = tid >> 6, lane = tid & 63;
    const int wr   = (wave >> 1) * 64, wc = (wave & 1) * 64;
    const int r    = lane & 15, g = lane >> 4;

    fx4 acc[4][4] = {};

    const int kper = K / kchunks;
    const int kbeg = kc * kper;
    const int nt   = kper / 32;

#define STAGE(buf, k0)                                                        \
    {                                                                         \
      _Pragma("unroll")                                                       \
      for (int i_ = 0; i_ < 2; ++i_) {                                        \
        const int o_   = (tid + i_*256) * 16;                                 \
        const int row_ = o_ >> 6;                                             \
        const int el_  = (o_ & 63) >> 1;                                      \
        const size_t ga_ = (size_t)(bm + row_) * lda + (k0) + el_;            \
        const size_t gb_ = (size_t)(bn + row_) * ldw + (k0) + el_;            \
        const int lb_ = (wave*64 + i_*256) * 16;                              \
        gld16(Ah + ga_, (char*)&sAh[buf][0] + lb_);                           \
        gld16(Al + ga_, (char*)&sAl[buf][0] + lb_);                           \
        gld16(Bh + gb_, (char*)&sBh[buf][0] + lb_);                           \
        gld16(Bl + gb_, (char*)&sBl[buf][0] + lb_);                           \
      }                                                                       \
    }

    int cur = 0;
    STAGE(0, kbeg)
    __syncthreads();

    for (int t = 0; t < nt; ++t) {
        if (t + 1 < nt) STAGE(cur ^ 1, kbeg + (t+1)*32)

        s16x8 a_h[4], a_l[4], b_h[4], b_l[4];
#pragma unroll
        for (int i = 0; i < 4; ++i) {
            const int ao = (wr + i*16 + r)*32 + g*8;
            const int bo = (wc + i*16 + r)*32 + g*8;
            a_h[i] = *(const s16x8*)&sAh[cur][ao];
            a_l[i] = *(const s16x8*)&sAl[cur][ao];
            b_h[i] = *(const s16x8*)&sBh[cur][bo];
            b_l[i] = *(const s16x8*)&sBl[cur][bo];
        }
#pragma unroll
        for (int i = 0; i < 4; ++i)
#pragma unroll
            for (int j = 0; j < 4; ++j) {
                acc[i][j] = __builtin_amdgcn_mfma_f32_16x16x32_bf16(a_h[i], b_h[j], acc[i][j], 0, 0, 0);
                acc[i][j] = __builtin_amdgcn_mfma_f32_16x16x32_bf16(a_l[i], b_h[j], acc[i][j], 0, 0, 0);
                acc[i][j] = __builtin_amdgcn_mfma_f32_16x16x32_bf16(a_h[i], b_l[j], acc[i][j], 0, 0, 0);
            }
        __syncthreads();
        cur ^= 1;
    }
#undef STAGE

    float* Cw = C + (size_t)kc * M * N;
#pragma unroll
    for (int i = 0; i < 4; ++i)
#pragma unroll
        for (int j = 0; j < 4; ++j)
#pragma unroll
            for (int reg = 0; reg < 4; ++reg) {
                const int row = bm + wr + i*16 + g*4 + reg;
                const int col = bn + wc + j*16 + r;
                float v = acc[i][j][reg];
                if (kchunks == 1 && bias) v += bias[col];
                Cw[(size_t)row * N + col] = v;
            }
}

// ---------------- persistent encoder: full-K 8-wave job, PLAIN loads ----------------
// Block = 512 thr = 8 waves; wave w owns rows [w*16,w*16+16); tile = 128 x 64
// cols at colbase; K = 1024 full. A = activation ring slot (plain loads, fresh
// address per step -> never stale, L2-cached & reused across blocks).
// W = read-only weights (plain loads, L2-resident per-XCD across steps).
// C-write via sc1 (astf) for cross-block visibility.
#define LOADK(k0, AH, AL, BH0, BL0)                                           \
    {                                                                         \
        AH = *(const s16x8*)(ah + (k0));                                      \
        AL = *(const s16x8*)(al + (k0));                                      \
        _Pragma("unroll")                                                     \
        for (int j = 0; j < 4; ++j) {                                         \
            const size_t boff = (size_t)(colbase + j*16 + r) * ldw + (k0) + g*8; \
            BH0[j] = *(const s16x8*)(Wh_ + boff);                             \
            BL0[j] = *(const s16x8*)(Wl_ + boff);                             \
        }                                                                     \
    }
#define COMPK(AH, AL, BH0, BL0)                                               \
    {                                                                         \
        _Pragma("unroll")                                                     \
        for (int j = 0; j < 4; ++j) {                                         \
            acc[j] = __builtin_amdgcn_mfma_f32_16x16x32_bf16(AH, BH0[j], acc[j], 0, 0, 0); \
            acc[j] = __builtin_amdgcn_mfma_f32_16x16x32_bf16(AL, BH0[j], acc[j], 0, 0, 0); \
            acc[j] = __builtin_amdgcn_mfma_f32_16x16x32_bf16(AH, BL0[j], acc[j], 0, 0, 0); \
        }                                                                     \
    }

__device__ __forceinline__ void job64(
    const ushort_t* __restrict__ Ah_, const ushort_t* __restrict__ Al_,
    const ushort_t* __restrict__ Wh_, const ushort_t* __restrict__ Wl_,
    int ldw,
    float* __restrict__ Cw, int ldc, int colbase)
{
    const int tid  = threadIdx.x;
    const int wave = tid >> 6, lane = tid & 63;
    const int wrow = wave * 16;
    const int r    = lane & 15, g = lane >> 4;
    fx4 acc[4] = {};

    const ushort_t* ah = Ah_ + (size_t)(wrow + r) * H_ + g*8;
    const ushort_t* al = Al_ + (size_t)(wrow + r) * H_ + g*8;

    s16x8 ah0, al0, ah1, al1, bh0[4], bl0[4], bh1[4], bl1[4];
    LOADK(0, ah0, al0, bh0, bl0)
    for (int kt = 0; kt < 32; kt += 2) {
        LOADK((kt+1)*32, ah1, al1, bh1, bl1)
        COMPK(ah0, al0, bh0, bl0)
        if (kt + 2 < 32) LOADK((kt+2)*32, ah0, al0, bh0, bl0)
        COMPK(ah1, al1, bh1, bl1)
    }
#pragma unroll
    for (int j = 0; j < 4; ++j)
#pragma unroll
        for (int reg = 0; reg < 4; ++reg)
            astf(&Cw[(size_t)(wrow + g*4 + reg) * ldc + colbase + j*16 + r], acc[j][reg]);
}
#undef LOADK
#undef COMPK

// Two-level grid barrier, ALL RELAXED (round-7 proven).
__device__ __forceinline__ void gbar(int* bar, int* lg) {
    __syncthreads();
    if (threadIdx.x == 0) {
        const int g = *lg;
        const int grp = blockIdx.x >> 4;
        const int p1 = __hip_atomic_fetch_add(&bar[grp*16], 1, __ATOMIC_RELAXED,
                                              __HIP_MEMORY_SCOPE_AGENT);
        if (p1 == 15) {
            const int p2 = __hip_atomic_fetch_add(&bar[BAR_MASTER], 1, __ATOMIC_RELAXED,
                                                  __HIP_MEMORY_SCOPE_AGENT);
            if (p2 == 15) {
                for (int g2 = 0; g2 < 16; ++g2)
                    __hip_atomic_store(&bar[g2*16], 0, __ATOMIC_RELAXED, __HIP_MEMORY_SCOPE_AGENT);
                __hip_atomic_store(&bar[BAR_MASTER], 0, __ATOMIC_RELAXED, __HIP_MEMORY_SCOPE_AGENT);
                __hip_atomic_store(&bar[BAR_GEN], g + 1, __ATOMIC_RELAXED, __HIP_MEMORY_SCOPE_AGENT);
            } else {
                while (__hip_atomic_load(&bar[BAR_GEN], __ATOMIC_RELAXED,
                                         __HIP_MEMORY_SCOPE_AGENT) == g)
                    __builtin_amdgcn_s_sleep(2);
            }
        } else {
            while (__hip_atomic_load(&bar[BAR_GEN], __ATOMIC_RELAXED,
                                     __HIP_MEMORY_SCOPE_AGENT) == g)
                __builtin_amdgcn_s_sleep(2);
        }
        *lg = g + 1;
    }
    __syncthreads();
}

// decoder-GRU update inside encoder, full-K inputs (no partials)
__device__ __forceinline__ void dec_update2s(int base,
    const float* __restrict__ gi2s, const float* __restrict__ gh2s,
    const float* __restrict__ dec_bih, const float* __restrict__ dec_bhh,
    float* __restrict__ dh, ushort_t* __restrict__ dhh_t, ushort_t* __restrict__ dhl_t)
{
    const int b = base >> 10, j = base & (H_ - 1);
    const float* gp = gi2s + (size_t)b * G3;
    const float* hp = gh2s + (size_t)b * G3;
    float2 a;
    float2 ir = *(const float2*)&dec_bih[j];
    a = u2f2(ald64(&gp[j]));      ir.x += a.x; ir.y += a.y;
    float2 iz = *(const float2*)&dec_bih[H_+j];
    a = u2f2(ald64(&gp[H_+j]));   iz.x += a.x; iz.y += a.y;
    float2 in2 = *(const float2*)&dec_bih[2*H_+j];
    a = u2f2(ald64(&gp[2*H_+j])); in2.x += a.x; in2.y += a.y;
    float2 hr = *(const float2*)&dec_bhh[j];
    a = u2f2(ald64(&hp[j]));      hr.x += a.x; hr.y += a.y;
    float2 hz = *(const float2*)&dec_bhh[H_+j];
    a = u2f2(ald64(&hp[H_+j]));   hz.x += a.x; hz.y += a.y;
    float2 hn = *(const float2*)&dec_bhh[2*H_+j];
    a = u2f2(ald64(&hp[2*H_+j])); hn.x += a.x; hn.y += a.y;
    float2 old = *(const float2*)&dh[base];
    const float v0 = gru_elem(ir.x, iz.x, in2.x, hr.x, hz.x, hn.x, old.x);
    const float v1 = gru_elem(ir.y, iz.y, in2.y, hr.y, hz.y, hn.y, old.y);
    *(float2*)&dh[base] = make_float2(v0, v1);
    ushort_t h0,l0,h1,l1;
    split1(v0,h0,l0); split1(v1,h1,l1);
    ast32(&dhh_t[base], (unsigned)h0 | ((unsigned)h1 << 16));
    ast32(&dhl_t[base], (unsigned)l0 | ((unsigned)l1 << 16));
}

// ---------------- persistent encoder scan (512 thr, KSPLIT=1, rings) ----------------
__global__ __launch_bounds__(512) void enc_persist(
    const float* __restrict__ gi,
    const ushort_t* __restrict__ Whh_h, const ushort_t* __restrict__ Whh_l,
    const ushort_t* __restrict__ l1h,   const ushort_t* __restrict__ l1l,
    const ushort_t* __restrict__ dWih_h,const ushort_t* __restrict__ dWih_l,
    const ushort_t* __restrict__ dWhh_h,const ushort_t* __restrict__ dWhh_l,
    const float* __restrict__ enc_bhh,  const float* __restrict__ lin1_b,
    const float* __restrict__ dec_bih,  const float* __restrict__ dec_bhh,
    float* __restrict__ eh, float* __restrict__ dh,
    ushort_t* __restrict__ ehh_r, ushort_t* __restrict__ ehl_r,
    ushort_t* __restrict__ dhh_r, ushort_t* __restrict__ dhl_r,
    ushort_t* __restrict__ uh_r,  ushort_t* __restrict__ ul_r,
    float* __restrict__ ghs, float* __restrict__ us,
    float* __restrict__ gi2s, float* __restrict__ gh2s,
    int* __restrict__ bar)
{
    const int bid = blockIdx.x;
    const int tid = threadIdx.x;
    int lg = 0;

    for (int t = 0; t < T_; ++t) {
        ushort_t* ehh_t = ehh_r + (size_t)t*B_*H_;
        ushort_t* ehl_t = ehl_r + (size_t)t*B_*H_;
        ushort_t* dhh_t = dhh_r + (size_t)t*B_*H_;
        ushort_t* dhl_t = dhl_r + (size_t)t*B_*H_;
        ushort_t* uh_t  = uh_r  + (size_t)t*B_*H_;
        ushort_t* ul_t  = ul_r  + (size_t)t*B_*H_;

        // ---- phase A (waves 0-3): eh <- GRU(gi[t], ghs) ; dh <- GRU [lagged] ----
        if (tid < 256) {
            const int base = bid * 512 + tid * 2;
            const int b = base >> 10, j = base & (H_ - 1);
            const float* girow = gi + ((size_t)(b * T_ + t)) * G3;
            const float* gr = ghs + (size_t)b * G3;
            float2 a;
            float2 ir = *(const float2*)&girow[j];
            float2 iz = *(const float2*)&girow[H_+j];
            float2 in2 = *(const float2*)&girow[2*H_+j];
            float2 hr = *(const float2*)&enc_bhh[j];
            a = u2f2(ald64(&gr[j]));      hr.x += a.x; hr.y += a.y;
            float2 hz = *(const float2*)&enc_bhh[H_+j];
            a = u2f2(ald64(&gr[H_+j]));   hz.x += a.x; hz.y += a.y;
            float2 hn = *(const float2*)&enc_bhh[2*H_+j];
            a = u2f2(ald64(&gr[2*H_+j])); hn.x += a.x; hn.y += a.y;
            float2 old = *(const float2*)&eh[base];
            const float v0 = gru_elem(ir.x, iz.x, in2.x, hr.x, hz.x, hn.x, old.x);
            const float v1 = gru_elem(ir.y, iz.y, in2.y, hr.y, hz.y, hn.y, old.y);
            *(float2*)&eh[base] = make_float2(v0, v1);
            ushort_t h0,l0,h1,l1;
            split1(v0,h0,l0); split1(v1,h1,l1);
            ast32(&ehh_t[base], (unsigned)h0 | ((unsigned)h1 << 16));
            ast32(&ehl_t[base], (unsigned)l0 | ((unsigned)l1 << 16));
            if (t > 0)
                dec_update2s(base, gi2s, gh2s, dec_bih, dec_bhh, dh, dhh_t, dhl_t);
        }
        gbar(bar, &lg);

        // ---- phase B (full-K, N-tile 64): ghs / us / gh2s ----
        if (bid < 48) {
            job64(ehh_t, ehl_t, Whh_h, Whh_l, H_, ghs, G3, bid*64);
        } else if (bid < 64) {
            job64(ehh_t, ehl_t, l1h, l1l, 2*H_, us, H_, (bid-48)*64);
        } else if (bid < 112) {
            job64(dhh_t, dhl_t, dWhh_h, dWhh_l, H_, gh2s, G3, (bid-64)*64);
        }
        gbar(bar, &lg);

        // ---- phase C1 (waves 0-3): u <- relu(us + lin1_b), split -> ring ----
        if (tid < 256) {
            const int base = bid * 512 + tid * 2;
            const int j = base & (H_ - 1);
            float2 v = *(const float2*)&lin1_b[j];
            float2 a = u2f2(ald64(&us[base]));
            v.x += a.x; v.y += a.y;
            v.x = fmaxf(v.x, 0.f); v.y = fmaxf(v.y, 0.f);
            ushort_t h0,l0,h1,l1;
            split1(v.x,h0,l0); split1(v.y,h1,l1);
            ast32(&uh_t[base], (unsigned)h0 | ((unsigned)h1 << 16));
            ast32(&ul_t[base], (unsigned)l0 | ((unsigned)l1 << 16));
        }
        gbar(bar, &lg);

        // ---- phase C2 (full-K): gi2s <- u@dWih^T ----
        if (bid < 48) {
            job64(uh_t, ul_t, dWih_h, dWih_l, H_, gi2s, G3, bid*64);
        }
        gbar(bar, &lg);
    }

    // tail: finish dec GRU of step T-1 (writes ring slot T for decoder)
    if (tid < 256) {
        const int base = bid * 512 + tid * 2;
        dec_update2s(base, gi2s, gh2s, dec_bih, dec_bhh, dh,
                     dhh_r + (size_t)T_*B_*H_, dhl_r + (size_t)T_*B_*H_);
    }
}

// ---------------- decoder elementwise kernels (unchanged) ----------------
__global__ __launch_bounds__(256) void gru_update2(
    const float* __restrict__ GI, int gi_rstride, int gi_nsplit,
    const float* __restrict__ bih,
    const float* __restrict__ GHp, const float* __restrict__ bhh,
    float* __restrict__ h, ushort_t* __restrict__ hh, ushort_t* __restrict__ hl)
{
    const int idx = blockIdx.x * 256 + threadIdx.x;
    const int b = idx >> 10;
    const int j = idx & (H_ - 1);
    float ir, iz, inn;
    if (gi_nsplit == 0) {
        const float* gi = GI + (size_t)b * gi_rstride;
        ir = gi[j]; iz = gi[H_ + j]; inn = gi[2*H_ + j];
    } else {
        ir = bih[j]; iz = bih[H_ + j]; inn = bih[2*H_ + j];
        const float* p = GI + (size_t)b * G3;
#pragma unroll
        for (int s = 0; s < KSPLIT; ++s) {
            ir += p[j]; iz += p[H_ + j]; inn += p[2*H_ + j];
            p += (size_t)B_ * G3;
        }
    }
    float hr = bhh[j], hz = bhh[H_ + j], hn = bhh[2*H_ + j];
    const float* q = GHp + (size_t)b * G3;
#pragma unroll
    for (int s = 0; s < KSPLIT; ++s) {
        hr += q[j]; hz += q[H_ + j]; hn += q[2*H_ + j];
        q += (size_t)B_ * G3;
    }
    const float v = gru_elem(ir, iz, inn, hr, hz, hn, h[idx]);
    h[idx] = v;
    split1(v, hh[idx], hl[idx]);
}

__global__ __launch_bounds__(256) void relu_combine(
    const float* __restrict__ Up, const float* __restrict__ bias,
    ushort_t* __restrict__ uh, ushort_t* __restrict__ ul)
{
    const int idx = blockIdx.x * 256 + threadIdx.x;
    const int j = idx & (H_ - 1);
    float v = bias[j];
#pragma unroll
    for (int s = 0; s < KSPLIT; ++s) v += Up[(size_t)s * B_ * H_ + idx];
    v = fmaxf(v, 0.f);
    split1(v, uh[idx], ul[idx]);
}

__global__ __launch_bounds__(256) void cat_eh_emb(
    const ushort_t* __restrict__ ehh, const ushort_t* __restrict__ ehl,
    const float* __restrict__ embed, const int* __restrict__ word,
    ushort_t* __restrict__ cath, ushort_t* __restrict__ catl)
{
    const int idx = blockIdx.x * 256 + threadIdx.x;
    const int b = idx >> 11;
    const int j = idx & (2*H_ - 1);
    if (j < H_) {
        cath[idx] = ehh[b * H_ + j];
        catl[idx] = ehl[b * H_ + j];
    } else {
        float v = embed[(size_t)word[b] * H_ + (j - H_)];
        split1(v, cath[idx], catl[idx]);
    }
}

// ---------------- init ----------------
__global__ __launch_bounds__(256) void init_state(
    float* __restrict__ eh, float* __restrict__ dh,
    ushort_t* __restrict__ dhh0, ushort_t* __restrict__ dhl0,
    int* __restrict__ word, float* __restrict__ out,
    float* __restrict__ ghs, int* __restrict__ bar)
{
    const int idx = blockIdx.x * 256 + threadIdx.x;
    if (idx < B_*G3) ghs[idx] = 0.f;
    if (idx < B_*H_) {
        eh[idx] = 0.f; dh[idx] = 0.f;
        dhh0[idx] = 0; dhl0[idx] = 0;
    }
    if (idx < B_)   word[idx] = 1;
    if (idx < 21)   out[idx] = 0.f;
    if (idx < 512)  bar[idx] = 0;
}

// ---------------- log-softmax + argmax + loss over 2 logit partials ----------------
__global__ __launch_bounds__(256) void softmax_loss(
    const float* __restrict__ logp, const float* __restrict__ l2b,
    const int* __restrict__ target, int s, int* __restrict__ word,
    float* __restrict__ out)
{
    const int b = blockIdx.x;
    const int t = threadIdx.x;
    const float* p0 = logp + (size_t)b * VP;
    const float* p1 = p0 + (size_t)B_ * VP;
    __shared__ float sv[256];
    __shared__ int   si[256];
    __shared__ float ss[256];

    float best = -FLT_MAX; int bi = 0;
    for (int j = t; j < V_; j += 256) {
        float v = p0[j] + p1[j] + l2b[j];
        if (v > best) { best = v; bi = j; }
    }
    sv[t] = best; si[t] = bi;
    __syncthreads();
    for (int off = 128; off > 0; off >>= 1) {
        if (t < off) {
            float v2 = sv[t + off]; int i2 = si[t + off];
            if (v2 > sv[t] || (v2 == sv[t] && i2 < si[t])) { sv[t] = v2; si[t] = i2; }
        }
        __syncthreads();
    }
    const float m = sv[0];
    const int amax = si[0];

    float sum = 0.f;
    for (int j = t; j < V_; j += 256) sum += expf(p0[j] + p1[j] + l2b[j] - m);
    ss[t] = sum;
    __syncthreads();
    for (int off = 128; off > 0; off >>= 1) {
        if (t < off) ss[t] += ss[t + off];
        __syncthreads();
    }
    if (t == 0) {
        const float lse = m + logf(ss[0]);
        const int tgt = target[b * S_ + s];
        const float logit_t = p0[tgt] + p1[tgt] + l2b[tgt];
        atomicAdd(&out[0], -(logit_t - lse) * (1.0f / (float)B_));
        word[b] = amax;
        if (b == 0) out[1 + s]  = (float)amax;
        if (b == 1) out[11 + s] = (float)amax;
    }
}

// ---------------- host helpers ----------------
static inline void launch_x3(hipStream_t st,
    const ushort_t* Ah, const ushort_t* Al, int lda,
    const ushort_t* Bh, const ushort_t* Bl, int ldw,
    const float* bias, float* C, int M, int N, int K, int kchunks)
{
    dim3 grid(N/128, M/128, kchunks);
    gemm_x3<<<grid, 256, 0, st>>>(Ah, Al, lda, Bh, Bl, ldw, bias, C, M, N, K, kchunks,
                                  nullptr, nullptr, nullptr, nullptr, nullptr);
}

static inline void launch_x3_dual(hipStream_t st,
    const ushort_t* Ah, const ushort_t* Al,
    const ushort_t* Bh, const ushort_t* Bl, float* C,
    const ushort_t* A2h, const ushort_t* A2l,
    const ushort_t* B2h, const ushort_t* B2l, float* C2,
    int M, int N, int K, int kchunks)
{
    dim3 grid(N/128, M/128, 2*kchunks);
    gemm_x3<<<grid, 256, 0, st>>>(Ah, Al, H_, Bh, Bl, H_, nullptr, C, M, N, K, kchunks,
                                  A2h, A2l, B2h, B2l, C2);
}

extern "C" void kernel_launch(void* const* d_in, const int* in_sizes, int n_in,
                              void* d_out, int out_size, void* d_ws, size_t ws_size,
                              hipStream_t stream)
{
    const float* data    = (const float*)d_in[0];
    const int*   target  = (const int*)  d_in[2];
    const float* enc_Wih = (const float*)d_in[4];
    const float* enc_Whh = (const float*)d_in[5];
    const float* enc_bih = (const float*)d_in[6];
    const float* enc_bhh = (const float*)d_in[7];
    const float* dec_Wih = (const float*)d_in[8];
    const float* dec_Whh = (const float*)d_in[9];
    const float* dec_bih = (const float*)d_in[10];
    const float* dec_bhh = (const float*)d_in[11];
    const float* lin1_W  = (const float*)d_in[12];
    const float* lin1_b  = (const float*)d_in[13];
    const float* lin2_W  = (const float*)d_in[14];
    const float* lin2_b  = (const float*)d_in[15];
    const float* embed   = (const float*)d_in[16];
    float* out = (float*)d_out;

    float *gi, *eh, *dh, *logitsp, *ghp, *gi2p, *gh2p, *up;
    float *ghs, *gh2s, *gi2s, *us;
    ushort_t *Ah, *Al, *Bh, *Bl, *Whh_h, *Whh_l, *dWih_h, *dWih_l, *dWhh_h, *dWhh_l;
    ushort_t *l1h, *l1l, *l2h, *l2l, *uh, *ul, *cath, *catl;
    ushort_t *ehh_r, *ehl_r, *dhh_r, *dhl_r, *uh_r, *ul_r;
    int *word, *bar;
    hipGetSymbolAddress((void**)&gi,     HIP_SYMBOL(g_gi));
    hipGetSymbolAddress((void**)&Ah,     HIP_SYMBOL(g_Ah));
    hipGetSymbolAddress((void**)&Al,     HIP_SYMBOL(g_Al));
    hipGetSymbolAddress((void**)&Bh,     HIP_SYMBOL(g_Bh));
    hipGetSymbolAddress((void**)&Bl,     HIP_SYMBOL(g_Bl));
    hipGetSymbolAddress((void**)&Whh_h,  HIP_SYMBOL(g_Whh_h));
    hipGetSymbolAddress((void**)&Whh_l,  HIP_SYMBOL(g_Whh_l));
    hipGetSymbolAddress((void**)&dWih_h, HIP_SYMBOL(g_dWih_h));
    hipGetSymbolAddress((void**)&dWih_l, HIP_SYMBOL(g_dWih_l));
    hipGetSymbolAddress((void**)&dWhh_h, HIP_SYMBOL(g_dWhh_h));
    hipGetSymbolAddress((void**)&dWhh_l, HIP_SYMBOL(g_dWhh_l));
    hipGetSymbolAddress((void**)&l1h,    HIP_SYMBOL(g_l1h));
    hipGetSymbolAddress((void**)&l1l,    HIP_SYMBOL(g_l1l));
    hipGetSymbolAddress((void**)&l2h,    HIP_SYMBOL(g_l2h));
    hipGetSymbolAddress((void**)&l2l,    HIP_SYMBOL(g_l2l));
    hipGetSymbolAddress((void**)&ghp,    HIP_SYMBOL(g_ghp));
    hipGetSymbolAddress((void**)&gi2p,   HIP_SYMBOL(g_gi2p));
    hipGetSymbolAddress((void**)&gh2p,   HIP_SYMBOL(g_gh2p));
    hipGetSymbolAddress((void**)&up,     HIP_SYMBOL(g_up));
    hipGetSymbolAddress((void**)&ghs,    HIP_SYMBOL(g_ghs));
    hipGetSymbolAddress((void**)&gh2s,   HIP_SYMBOL(g_gh2s));
    hipGetSymbolAddress((void**)&gi2s,   HIP_SYMBOL(g_gi2s));
    hipGetSymbolAddress((void**)&us,     HIP_SYMBOL(g_us));
    hipGetSymbolAddress((void**)&eh,     HIP_SYMBOL(g_eh));
    hipGetSymbolAddress((void**)&dh,     HIP_SYMBOL(g_dh));
    hipGetSymbolAddress((void**)&ehh_r,  HIP_SYMBOL(g_ehh_r));
    hipGetSymbolAddress((void**)&ehl_r,  HIP_SYMBOL(g_ehl_r));
    hipGetSymbolAddress((void**)&dhh_r,  HIP_SYMBOL(g_dhh_r));
    hipGetSymbolAddress((void**)&dhl_r,  HIP_SYMBOL(g_dhl_r));
    hipGetSymbolAddress((void**)&uh_r,   HIP_SYMBOL(g_uh_r));
    hipGetSymbolAddress((void**)&ul_r,   HIP_SYMBOL(g_ul_r));
    hipGetSymbolAddress((void**)&uh,     HIP_SYMBOL(g_uh));
    hipGetSymbolAddress((void**)&ul,     HIP_SYMBOL(g_ul));
    hipGetSymbolAddress((void**)&cath,   HIP_SYMBOL(g_cath));
    hipGetSymbolAddress((void**)&catl,   HIP_SYMBOL(g_catl));
    hipGetSymbolAddress((void**)&logitsp,HIP_SYMBOL(g_logitsp));
    hipGetSymbolAddress((void**)&word,   HIP_SYMBOL(g_word));
    hipGetSymbolAddress((void**)&bar,    HIP_SYMBOL(g_bar));

    ushort_t* ehh_dec = ehh_r + (size_t)(T_-1)*B_*H_;
    ushort_t* ehl_dec = ehl_r + (size_t)(T_-1)*B_*H_;
    ushort_t* dhh_dec = dhh_r + (size_t)T_*B_*H_;
    ushort_t* dhl_dec = dhl_r + (size_t)T_*B_*H_;

    init_state<<<6144, 256, 0, stream>>>(eh, dh,
        dhh_r, dhl_r, word, out, ghs, bar);

    // bf16 hi/lo splits
    split_bf16<<<(B_*T_*D_/4 + 255)/256, 256, 0, stream>>>(data,    Ah, Al, B_*T_*D_/4);
    split_bf16<<<(G3*D_/4   + 255)/256, 256, 0, stream>>>(enc_Wih, Bh, Bl, G3*D_/4);
    split_bf16<<<(G3*H_/4   + 255)/256, 256, 0, stream>>>(enc_Whh, Whh_h, Whh_l, G3*H_/4);
    split_bf16<<<(G3*H_/4   + 255)/256, 256, 0, stream>>>(dec_Wih, dWih_h, dWih_l, G3*H_/4);
    split_bf16<<<(G3*H_/4   + 255)/256, 256, 0, stream>>>(dec_Whh, dWhh_h, dWhh_l, G3*H_/4);
    split_bf16<<<(H_*2*H_/4 + 255)/256, 256, 0, stream>>>(lin1_W,  l1h, l1l, H_*2*H_/4);
    split_bf16<<<(V_*H_/4   + 255)/256, 256, 0, stream>>>(lin2_W,  l2h, l2l, V_*H_/4);

    // gi[B*T][3H] = data @ enc_Wih^T + enc_bih
    launch_x3(stream, Ah, Al, D_, Bh, Bl, D_, enc_bih, gi, B_*T_, G3, D_, 1);

    // ---------------- encoder scan: ONE persistent launch ----------------
    enc_persist<<<NBLK, 512, 0, stream>>>(
        gi, Whh_h, Whh_l, l1h, l1l, dWih_h, dWih_l, dWhh_h, dWhh_l,
        enc_bhh, lin1_b, dec_bih, dec_bhh,
        eh, dh,
        ehh_r, ehl_r, dhh_r, dhl_r, uh_r, ul_r,
        ghs, us, gi2s, gh2s, bar);

    // ---------------- decoder scan ----------------
    for (int s = 0; s < S_; ++s) {
        launch_x3(stream, ehh_dec, ehl_dec, H_, Whh_h, Whh_l, H_, nullptr, ghp, B_, G3, H_, KSPLIT);
        gru_update2<<<512, 256, 0, stream>>>(enc_bih, 0, 0, nullptr,
                                             ghp, enc_bhh, eh, ehh_dec, ehl_dec);
        cat_eh_emb<<<1024, 256, 0, stream>>>(ehh_dec, ehl_dec, embed, word, cath, catl);
        launch_x3(stream, cath, catl, 2*H_, l1h, l1l, 2*H_, nullptr, up, B_, H_, 2*H_, KSPLIT);
        relu_combine<<<512, 256, 0, stream>>>(up, lin1_b, uh, ul);
        launch_x3_dual(stream, uh, ul, dWih_h, dWih_l, gi2p,
                               dhh_dec, dhl_dec, dWhh_h, dWhh_l, gh2p, B_, G3, H_, KSPLIT);
        gru_update2<<<512, 256, 0, stream>>>(gi2p, 0, KSPLIT, dec_bih,
                                             gh2p, dec_bhh, dh, dhh_dec, dhl_dec);
        launch_x3(stream, dhh_dec, dhl_dec, H_, l2h, l2l, H_, nullptr, logitsp, B_, VP, H_, 2);
        softmax_loss<<<B_, 256, 0, stream>>>(logitsp, lin2_b, target, s, word, out);
    }
}

// Round 11
// 7998.215 us; speedup vs baseline: 2.0007x; 2.0007x over previous
//
#include <hip/hip_runtime.h>
#include <math.h>
#include <float.h>

#define B_ 128
#define T_ 80
#define D_ 4096
#define H_ 1024
#define V_ 6000
#define VP 6016          // V padded to 128
#define S_ 10
#define G3 (3*H_)
#define KSPLIT 4         // decoder standalone GEMMs only
#define NBLK 256         // persistent-kernel grid
#define BAR_MASTER 320
#define BAR_GEN    336

typedef unsigned short ushort_t;
typedef unsigned long long ull_t;
typedef __attribute__((ext_vector_type(8))) short s16x8;
typedef __attribute__((ext_vector_type(4))) float fx4;

// ---------------- static device scratch ----------------
__device__ float    g_gi[(size_t)B_*T_*G3];        // precomputed x@Wih^T+bih, all t
__device__ ushort_t g_Ah[(size_t)B_*T_*D_];
__device__ ushort_t g_Al[(size_t)B_*T_*D_];
__device__ ushort_t g_Bh[(size_t)G3*D_];
__device__ ushort_t g_Bl[(size_t)G3*D_];
__device__ ushort_t g_Whh_h[G3*H_],  g_Whh_l[G3*H_];
__device__ ushort_t g_dWih_h[G3*H_], g_dWih_l[G3*H_];
__device__ ushort_t g_dWhh_h[G3*H_], g_dWhh_l[G3*H_];
__device__ ushort_t g_l1h[H_*2*H_],  g_l1l[H_*2*H_];
__device__ ushort_t g_l2h[(size_t)VP*H_], g_l2l[(size_t)VP*H_];
// decoder split-K partials (standalone kernels only)
__device__ float g_ghp [KSPLIT*B_*G3];
__device__ float g_gi2p[KSPLIT*B_*G3];
__device__ float g_gh2p[KSPLIT*B_*G3];
__device__ float g_up  [KSPLIT*B_*H_];
// encoder full-K output RINGS (sc1-written, PLAIN-read; slot t+1 = produced in step t)
__device__ float g_ghs_r [(size_t)(T_+1)*B_*G3];   // eh@Whh^T
__device__ float g_gh2s_r[(size_t)(T_+1)*B_*G3];   // dh@dWhh^T
__device__ float g_gi2s_r[(size_t)(T_+1)*B_*G3];   // u@dWih^T
__device__ float g_us_r  [(size_t)(T_+1)*B_*H_];   // eh@W1a^T
// fp32 states (same-thread access inside enc_persist)
__device__ float g_eh[B_*H_];
__device__ float g_dh[B_*H_];
// per-step activation RINGS (sc1-written, PLAIN-read)
__device__ ushort_t g_ehh_r[(size_t)T_*B_*H_],     g_ehl_r[(size_t)T_*B_*H_];
__device__ ushort_t g_dhh_r[(size_t)(T_+1)*B_*H_], g_dhl_r[(size_t)(T_+1)*B_*H_];
__device__ ushort_t g_uh_r[(size_t)T_*B_*H_],      g_ul_r[(size_t)T_*B_*H_];
// decoder scratch
__device__ ushort_t g_uh[B_*H_],  g_ul[B_*H_];
__device__ ushort_t g_cath[B_*2*H_], g_catl[B_*2*H_];
__device__ float g_logitsp[2*B_*VP];
__device__ int   g_word[B_];
__device__ int   g_bar[512];

// ---------------- coherent (sc1) write helpers: relaxed agent atomics ----------------
__device__ __forceinline__ void ast32(void* p, unsigned v) {
    __hip_atomic_store((unsigned*)p, v, __ATOMIC_RELAXED, __HIP_MEMORY_SCOPE_AGENT);
}
__device__ __forceinline__ void astf(float* p, float v) {
    ast32(p, __float_as_uint(v));
}

// ---------------- fp32 -> bf16 hi/lo split (RNE) ----------------
__device__ __forceinline__ void split1(float x, ushort_t& hi, ushort_t& lo) {
    unsigned u = __float_as_uint(x);
    unsigned rh = u + 0x7FFF + ((u >> 16) & 1);
    hi = (ushort_t)(rh >> 16);
    float fhi = __uint_as_float((unsigned)hi << 16);
    float d = x - fhi;
    unsigned u2 = __float_as_uint(d);
    unsigned rl = u2 + 0x7FFF + ((u2 >> 16) & 1);
    lo = (ushort_t)(rl >> 16);
}

__global__ __launch_bounds__(256) void split_bf16(
    const float* __restrict__ x, ushort_t* __restrict__ hi,
    ushort_t* __restrict__ lo, int n4)
{
    int i = blockIdx.x * 256 + threadIdx.x;
    if (i >= n4) return;
    float4 v = ((const float4*)x)[i];
    ushort_t h0,h1,h2,h3,l0,l1,l2,l3;
    split1(v.x,h0,l0); split1(v.y,h1,l1); split1(v.z,h2,l2); split1(v.w,h3,l3);
    ushort_t* hp = hi + (size_t)i*4;  hp[0]=h0; hp[1]=h1; hp[2]=h2; hp[3]=h3;
    ushort_t* lp = lo + (size_t)i*4;  lp[0]=l0; lp[1]=l1; lp[2]=l2; lp[3]=l3;
}

// ---------------- async global->LDS 16B ----------------
__device__ __forceinline__ void gld16(const ushort_t* g, void* l) {
    __builtin_amdgcn_global_load_lds(
        (const __attribute__((address_space(1))) void*)(const void*)g,
        (__attribute__((address_space(3))) void*)l, 16, 0, 0);
}

// ---------------- GRU elementwise core ----------------
__device__ __forceinline__ float gru_elem(float ir,float iz,float inn,
                                          float hr,float hz,float hn,float hprev){
    const float r = 1.f/(1.f+expf(-(ir+hr)));
    const float z = 1.f/(1.f+expf(-(iz+hz)));
    const float n = tanhf(inn + r*hn);
    return (1.f-z)*n + z*hprev;
}

// ---------------- standalone bf16x3 MFMA GEMM (precompute + decoder) ----------------
__global__ __launch_bounds__(256) void gemm_x3(
    const ushort_t* __restrict__ Ah, const ushort_t* __restrict__ Al, int lda,
    const ushort_t* __restrict__ Bh, const ushort_t* __restrict__ Bl, int ldw,
    const float* __restrict__ bias,
    float* __restrict__ C,
    int M, int N, int K, int kchunks,
    const ushort_t* __restrict__ A2h, const ushort_t* __restrict__ A2l,
    const ushort_t* __restrict__ B2h, const ushort_t* __restrict__ B2l,
    float* __restrict__ C2)
{
    int z = blockIdx.z;
    int kc = z;
    if (z >= kchunks) { kc = z - kchunks; Ah=A2h; Al=A2l; Bh=B2h; Bl=B2l; C=C2; }

    __shared__ ushort_t sAh[2][128*32], sAl[2][128*32];
    __shared__ ushort_t sBh[2][128*32], sBl[2][128*32];

    const int tid  = threadIdx.x;
    const int bm   = blockIdx.y * 128, bn = blockIdx.x * 128;
    const int wave = tid >> 6, lane = tid & 63;
    const int wr   = (wave >> 1) * 64, wc = (wave & 1) * 64;
    const int r    = lane & 15, g = lane >> 4;

    fx4 acc[4][4] = {};

    const int kper = K / kchunks;
    const int kbeg = kc * kper;
    const int nt   = kper / 32;

#define STAGE(buf, k0)                                                        \
    {                                                                         \
      _Pragma("unroll")                                                       \
      for (int i_ = 0; i_ < 2; ++i_) {                                        \
        const int o_   = (tid + i_*256) * 16;                                 \
        const int row_ = o_ >> 6;                                             \
        const int el_  = (o_ & 63) >> 1;                                      \
        const size_t ga_ = (size_t)(bm + row_) * lda + (k0) + el_;            \
        const size_t gb_ = (size_t)(bn + row_) * ldw + (k0) + el_;            \
        const int lb_ = (wave*64 + i_*256) * 16;                              \
        gld16(Ah + ga_, (char*)&sAh[buf][0] + lb_);                           \
        gld16(Al + ga_, (char*)&sAl[buf][0] + lb_);                           \
        gld16(Bh + gb_, (char*)&sBh[buf][0] + lb_);                           \
        gld16(Bl + gb_, (char*)&sBl[buf][0] + lb_);                           \
      }                                                                       \
    }

    int cur = 0;
    STAGE(0, kbeg)
    __syncthreads();

    for (int t = 0; t < nt; ++t) {
        if (t + 1 < nt) STAGE(cur ^ 1, kbeg + (t+1)*32)

        s16x8 a_h[4], a_l[4], b_h[4], b_l[4];
#pragma unroll
        for (int i = 0; i < 4; ++i) {
            const int ao = (wr + i*16 + r)*32 + g*8;
            const int bo = (wc + i*16 + r)*32 + g*8;
            a_h[i] = *(const s16x8*)&sAh[cur][ao];
            a_l[i] = *(const s16x8*)&sAl[cur][ao];
            b_h[i] = *(const s16x8*)&sBh[cur][bo];
            b_l[i] = *(const s16x8*)&sBl[cur][bo];
        }
#pragma unroll
        for (int i = 0; i < 4; ++i)
#pragma unroll
            for (int j = 0; j < 4; ++j) {
                acc[i][j] = __builtin_amdgcn_mfma_f32_16x16x32_bf16(a_h[i], b_h[j], acc[i][j], 0, 0, 0);
                acc[i][j] = __builtin_amdgcn_mfma_f32_16x16x32_bf16(a_l[i], b_h[j], acc[i][j], 0, 0, 0);
                acc[i][j] = __builtin_amdgcn_mfma_f32_16x16x32_bf16(a_h[i], b_l[j], acc[i][j], 0, 0, 0);
            }
        __syncthreads();
        cur ^= 1;
    }
#undef STAGE

    float* Cw = C + (size_t)kc * M * N;
#pragma unroll
    for (int i = 0; i < 4; ++i)
#pragma unroll
        for (int j = 0; j < 4; ++j)
#pragma unroll
            for (int reg = 0; reg < 4; ++reg) {
                const int row = bm + wr + i*16 + g*4 + reg;
                const int col = bn + wc + j*16 + r;
                float v = acc[i][j][reg];
                if (kchunks == 1 && bias) v += bias[col];
                Cw[(size_t)row * N + col] = v;
            }
}

// ---------------- persistent encoder: full-K 32-col jobs ----------------
// Block = 512 thr = 8 waves; output tile 128 rows (batch) x 32 cols (N),
// K = 1024 full. Wave w owns output rows [w*16, w*16+16).
// A: PLAIN loads from per-step ring slot (L2-cached; stale==identical).
// W (phase B): LDS-resident (XOR-swizzled), loaded ONCE per kernel.
// C-write: sc1 (astf) to fp32 ring slot.

__device__ __forceinline__ void job32(
    const ushort_t* __restrict__ Ah_, const ushort_t* __restrict__ Al_,
    const ushort_t* __restrict__ sWh, const ushort_t* __restrict__ sWl,
    float* __restrict__ Cw, int ldc, int colbase)
{
    const int tid  = threadIdx.x;
    const int wave = tid >> 6, lane = tid & 63;
    const int wrow = wave * 16;
    const int r    = lane & 15, g = lane >> 4;
    fx4 acc[2] = {};

    const ushort_t* ah = Ah_ + (size_t)(wrow + r) * H_ + g*8;
    const ushort_t* al = Al_ + (size_t)(wrow + r) * H_ + g*8;

#pragma unroll 4
    for (int kt = 0; kt < 32; ++kt) {
        s16x8 a_h = *(const s16x8*)(ah + kt*32);
        s16x8 a_l = *(const s16x8*)(al + kt*32);
#pragma unroll
        for (int j = 0; j < 2; ++j) {
            const int row  = j*16 + r;
            const int loff = row*1024 + ((((kt<<2)+g) ^ (row&7)) << 3);
            s16x8 b_h = *(const s16x8*)&sWh[loff];
            s16x8 b_l = *(const s16x8*)&sWl[loff];
            acc[j] = __builtin_amdgcn_mfma_f32_16x16x32_bf16(a_h, b_h, acc[j], 0, 0, 0);
            acc[j] = __builtin_amdgcn_mfma_f32_16x16x32_bf16(a_l, b_h, acc[j], 0, 0, 0);
            acc[j] = __builtin_amdgcn_mfma_f32_16x16x32_bf16(a_h, b_l, acc[j], 0, 0, 0);
        }
    }
#pragma unroll
    for (int j = 0; j < 2; ++j)
#pragma unroll
        for (int reg = 0; reg < 4; ++reg)
            astf(&Cw[(size_t)(wrow + g*4 + reg) * ldc + colbase + j*16 + r], acc[j][reg]);
}

// C2 variant: W streamed via PLAIN loads (read-only, L2-resident).
__device__ __forceinline__ void job32s(
    const ushort_t* __restrict__ Ah_, const ushort_t* __restrict__ Al_,
    const ushort_t* __restrict__ Wgh, const ushort_t* __restrict__ Wgl,
    float* __restrict__ Cw, int ldc, int colbase)
{
    const int tid  = threadIdx.x;
    const int wave = tid >> 6, lane = tid & 63;
    const int wrow = wave * 16;
    const int r    = lane & 15, g = lane >> 4;
    fx4 acc[2] = {};

    const ushort_t* ah = Ah_ + (size_t)(wrow + r) * H_ + g*8;
    const ushort_t* al = Al_ + (size_t)(wrow + r) * H_ + g*8;
    const ushort_t* w0h = Wgh + (size_t)(colbase + r) * H_ + g*8;
    const ushort_t* w0l = Wgl + (size_t)(colbase + r) * H_ + g*8;
    const ushort_t* w1h = w0h + (size_t)16 * H_;
    const ushort_t* w1l = w0l + (size_t)16 * H_;

#pragma unroll 4
    for (int kt = 0; kt < 32; ++kt) {
        s16x8 a_h = *(const s16x8*)(ah + kt*32);
        s16x8 a_l = *(const s16x8*)(al + kt*32);
        s16x8 b0h = *(const s16x8*)(w0h + kt*32);
        s16x8 b0l = *(const s16x8*)(w0l + kt*32);
        s16x8 b1h = *(const s16x8*)(w1h + kt*32);
        s16x8 b1l = *(const s16x8*)(w1l + kt*32);
        acc[0] = __builtin_amdgcn_mfma_f32_16x16x32_bf16(a_h, b0h, acc[0], 0, 0, 0);
        acc[0] = __builtin_amdgcn_mfma_f32_16x16x32_bf16(a_l, b0h, acc[0], 0, 0, 0);
        acc[0] = __builtin_amdgcn_mfma_f32_16x16x32_bf16(a_h, b0l, acc[0], 0, 0, 0);
        acc[1] = __builtin_amdgcn_mfma_f32_16x16x32_bf16(a_h, b1h, acc[1], 0, 0, 0);
        acc[1] = __builtin_amdgcn_mfma_f32_16x16x32_bf16(a_l, b1h, acc[1], 0, 0, 0);
        acc[1] = __builtin_amdgcn_mfma_f32_16x16x32_bf16(a_h, b1l, acc[1], 0, 0, 0);
    }
#pragma unroll
    for (int j = 0; j < 2; ++j)
#pragma unroll
        for (int reg = 0; reg < 4; ++reg)
            astf(&Cw[(size_t)(wrow + g*4 + reg) * ldc + colbase + j*16 + r], acc[j][reg]);
}

// Two-level grid barrier, ALL RELAXED (round-7 proven).
__device__ __forceinline__ void gbar(int* bar, int* lg) {
    __syncthreads();
    if (threadIdx.x == 0) {
        const int g = *lg;
        const int grp = blockIdx.x >> 4;
        const int p1 = __hip_atomic_fetch_add(&bar[grp*16], 1, __ATOMIC_RELAXED,
                                              __HIP_MEMORY_SCOPE_AGENT);
        if (p1 == 15) {
            const int p2 = __hip_atomic_fetch_add(&bar[BAR_MASTER], 1, __ATOMIC_RELAXED,
                                                  __HIP_MEMORY_SCOPE_AGENT);
            if (p2 == 15) {
                for (int g2 = 0; g2 < 16; ++g2)
                    __hip_atomic_store(&bar[g2*16], 0, __ATOMIC_RELAXED, __HIP_MEMORY_SCOPE_AGENT);
                __hip_atomic_store(&bar[BAR_MASTER], 0, __ATOMIC_RELAXED, __HIP_MEMORY_SCOPE_AGENT);
                __hip_atomic_store(&bar[BAR_GEN], g + 1, __ATOMIC_RELAXED, __HIP_MEMORY_SCOPE_AGENT);
            } else {
                while (__hip_atomic_load(&bar[BAR_GEN], __ATOMIC_RELAXED,
                                         __HIP_MEMORY_SCOPE_AGENT) == g)
                    __builtin_amdgcn_s_sleep(2);
            }
        } else {
            while (__hip_atomic_load(&bar[BAR_GEN], __ATOMIC_RELAXED,
                                     __HIP_MEMORY_SCOPE_AGENT) == g)
                __builtin_amdgcn_s_sleep(2);
        }
        *lg = g + 1;
    }
    __syncthreads();
}

// decoder-GRU update inside encoder: full-K inputs, PLAIN ring reads
__device__ __forceinline__ void dec_update2p(int base,
    const float* __restrict__ gi2, const float* __restrict__ gh2,
    const float* __restrict__ dec_bih, const float* __restrict__ dec_bhh,
    float* __restrict__ dh, ushort_t* __restrict__ dhh_t, ushort_t* __restrict__ dhl_t)
{
    const int b = base >> 10, j = base & (H_ - 1);
    const float* gp = gi2 + (size_t)b * G3;
    const float* hp = gh2 + (size_t)b * G3;
    float2 a;
    float2 ir = *(const float2*)&dec_bih[j];
    a = *(const float2*)&gp[j];      ir.x += a.x; ir.y += a.y;
    float2 iz = *(const float2*)&dec_bih[H_+j];
    a = *(const float2*)&gp[H_+j];   iz.x += a.x; iz.y += a.y;
    float2 in2 = *(const float2*)&dec_bih[2*H_+j];
    a = *(const float2*)&gp[2*H_+j]; in2.x += a.x; in2.y += a.y;
    float2 hr = *(const float2*)&dec_bhh[j];
    a = *(const float2*)&hp[j];      hr.x += a.x; hr.y += a.y;
    float2 hz = *(const float2*)&dec_bhh[H_+j];
    a = *(const float2*)&hp[H_+j];   hz.x += a.x; hz.y += a.y;
    float2 hn = *(const float2*)&dec_bhh[2*H_+j];
    a = *(const float2*)&hp[2*H_+j]; hn.x += a.x; hn.y += a.y;
    float2 old = *(const float2*)&dh[base];
    const float v0 = gru_elem(ir.x, iz.x, in2.x, hr.x, hz.x, hn.x, old.x);
    const float v1 = gru_elem(ir.y, iz.y, in2.y, hr.y, hz.y, hn.y, old.y);
    *(float2*)&dh[base] = make_float2(v0, v1);
    ushort_t h0,l0,h1,l1;
    split1(v0,h0,l0); split1(v1,h1,l1);
    ast32(&dhh_t[base], (unsigned)h0 | ((unsigned)h1 << 16));
    ast32(&dhl_t[base], (unsigned)l0 | ((unsigned)l1 << 16));
}

// ---------------- persistent encoder scan (512 thr, KSPLIT=1, all-plain reads) ----------------
__global__ __launch_bounds__(512) void enc_persist(
    const float* __restrict__ gi,
    const ushort_t* __restrict__ Whh_h, const ushort_t* __restrict__ Whh_l,
    const ushort_t* __restrict__ l1h,   const ushort_t* __restrict__ l1l,
    const ushort_t* __restrict__ dWih_h,const ushort_t* __restrict__ dWih_l,
    const ushort_t* __restrict__ dWhh_h,const ushort_t* __restrict__ dWhh_l,
    const float* __restrict__ enc_bhh,  const float* __restrict__ lin1_b,
    const float* __restrict__ dec_bih,  const float* __restrict__ dec_bhh,
    float* __restrict__ eh, float* __restrict__ dh,
    ushort_t* __restrict__ ehh_r, ushort_t* __restrict__ ehl_r,
    ushort_t* __restrict__ dhh_r, ushort_t* __restrict__ dhl_r,
    ushort_t* __restrict__ uh_r,  ushort_t* __restrict__ ul_r,
    float* __restrict__ ghs_r, float* __restrict__ us_r,
    float* __restrict__ gi2s_r, float* __restrict__ gh2s_r,
    int* __restrict__ bar)
{
    extern __shared__ ushort_t smw[];     // 128 KiB: hi [0,32768), lo [32768,65536)
    ushort_t* sWh = smw;
    ushort_t* sWl = smw + 32768;

    const int bid = blockIdx.x;
    const int tid = threadIdx.x;
    int lg = 0;

    // one-time: resident phase-B weight tile [32 rows][1024 K], XOR-swizzled.
    if (bid < 224) {
        const ushort_t *Wh, *Wl; int ldw, rowbase;
        if (bid < 96)       { Wh=Whh_h;  Wl=Whh_l;  ldw=H_;   rowbase=bid*32; }
        else if (bid < 128) { Wh=l1h;    Wl=l1l;    ldw=2*H_; rowbase=(bid-96)*32; }
        else                { Wh=dWhh_h; Wl=dWhh_l; ldw=H_;   rowbase=(bid-128)*32; }
        for (int c = tid; c < 4096; c += 512) {       // 4096 granules of 8 elems
            const int row = c >> 7, gr8 = c & 127;
            const size_t goff = (size_t)(rowbase + row) * ldw + gr8*8;
            const int    loff = row*1024 + ((gr8 ^ (row & 7)) << 3);
            *(s16x8*)&sWh[loff] = *(const s16x8*)(Wh + goff);
            *(s16x8*)&sWl[loff] = *(const s16x8*)(Wl + goff);
        }
    }
    __syncthreads();

    for (int t = 0; t < T_; ++t) {
        ushort_t* ehh_t = ehh_r + (size_t)t*B_*H_;
        ushort_t* ehl_t = ehl_r + (size_t)t*B_*H_;
        ushort_t* dhh_t = dhh_r + (size_t)t*B_*H_;   // holds dh_{t-1}
        ushort_t* dhl_t = dhl_r + (size_t)t*B_*H_;
        ushort_t* uh_t  = uh_r  + (size_t)t*B_*H_;
        ushort_t* ul_t  = ul_r  + (size_t)t*B_*H_;

        // ---- phase A (waves 0-3): eh <- GRU(gi[t], ghs[t]) ; dh <- GRU [lagged] ----
        if (tid < 256) {
            const int base = bid * 512 + tid * 2;
            const int b = base >> 10, j = base & (H_ - 1);
            const float* girow = gi + ((size_t)(b * T_ + t)) * G3;
            const float* gr = ghs_r + (size_t)t*B_*G3 + (size_t)b * G3;
            float2 a;
            float2 ir = *(const float2*)&girow[j];
            float2 iz = *(const float2*)&girow[H_+j];
            float2 in2 = *(const float2*)&girow[2*H_+j];
            float2 hr = *(const float2*)&enc_bhh[j];
            a = *(const float2*)&gr[j];      hr.x += a.x; hr.y += a.y;
            float2 hz = *(const float2*)&enc_bhh[H_+j];
            a = *(const float2*)&gr[H_+j];   hz.x += a.x; hz.y += a.y;
            float2 hn = *(const float2*)&enc_bhh[2*H_+j];
            a = *(const float2*)&gr[2*H_+j]; hn.x += a.x; hn.y += a.y;
            float2 old = *(const float2*)&eh[base];
            const float v0 = gru_elem(ir.x, iz.x, in2.x, hr.x, hz.x, hn.x, old.x);
            const float v1 = gru_elem(ir.y, iz.y, in2.y, hr.y, hz.y, hn.y, old.y);
            *(float2*)&eh[base] = make_float2(v0, v1);
            ushort_t h0,l0,h1,l1;
            split1(v0,h0,l0); split1(v1,h1,l1);
            ast32(&ehh_t[base], (unsigned)h0 | ((unsigned)h1 << 16));
            ast32(&ehl_t[base], (unsigned)l0 | ((unsigned)l1 << 16));
            if (t > 0)
                dec_update2p(base, gi2s_r + (size_t)t*B_*G3, gh2s_r + (size_t)t*B_*G3,
                             dec_bih, dec_bhh, dh, dhh_t, dhl_t);
        }
        gbar(bar, &lg);

        // ---- phase B (LDS-resident W, full K): ghs / us / gh2s -> slot t+1 ----
        if (bid < 96) {
            job32(ehh_t, ehl_t, sWh, sWl,
                  ghs_r + (size_t)(t+1)*B_*G3, G3, bid*32);
        } else if (bid < 128) {
            job32(ehh_t, ehl_t, sWh, sWl,
                  us_r + (size_t)(t+1)*B_*H_, H_, (bid-96)*32);
        } else if (bid < 224) {
            job32(dhh_t, dhl_t, sWh, sWl,
                  gh2s_r + (size_t)(t+1)*B_*G3, G3, (bid-128)*32);
        }
        gbar(bar, &lg);

        // ---- phase C1 (waves 0-3): u <- relu(us[t+1] + lin1_b) -> ring slot t ----
        if (tid < 256) {
            const int base = bid * 512 + tid * 2;
            const int j = base & (H_ - 1);
            const float* usrow = us_r + (size_t)(t+1)*B_*H_;
            float2 v = *(const float2*)&lin1_b[j];
            float2 a = *(const float2*)&usrow[base];
            v.x += a.x; v.y += a.y;
            v.x = fmaxf(v.x, 0.f); v.y = fmaxf(v.y, 0.f);
            ushort_t h0,l0,h1,l1;
            split1(v.x,h0,l0); split1(v.y,h1,l1);
            ast32(&uh_t[base], (unsigned)h0 | ((unsigned)h1 << 16));
            ast32(&ul_t[base], (unsigned)l0 | ((unsigned)l1 << 16));
        }
        gbar(bar, &lg);

        // ---- phase C2 (streamed dWih, full K): gi2s -> slot t+1 ----
        if (bid < 96) {
            job32s(uh_t, ul_t, dWih_h, dWih_l,
                   gi2s_r + (size_t)(t+1)*B_*G3, G3, bid*32);
        }
        gbar(bar, &lg);
    }

    // tail: finish dec GRU of step T-1 (ring slot T for decoder)
    if (tid < 256) {
        const int base = bid * 512 + tid * 2;
        dec_update2p(base, gi2s_r + (size_t)T_*B_*G3, gh2s_r + (size_t)T_*B_*G3,
                     dec_bih, dec_bhh, dh,
                     dhh_r + (size_t)T_*B_*H_, dhl_r + (size_t)T_*B_*H_);
    }
}

// ---------------- decoder elementwise kernels (unchanged) ----------------
__global__ __launch_bounds__(256) void gru_update2(
    const float* __restrict__ GI, int gi_rstride, int gi_nsplit,
    const float* __restrict__ bih,
    const float* __restrict__ GHp, const float* __restrict__ bhh,
    float* __restrict__ h, ushort_t* __restrict__ hh, ushort_t* __restrict__ hl)
{
    const int idx = blockIdx.x * 256 + threadIdx.x;
    const int b = idx >> 10;
    const int j = idx & (H_ - 1);
    float ir, iz, inn;
    if (gi_nsplit == 0) {
        const float* gi = GI + (size_t)b * gi_rstride;
        ir = gi[j]; iz = gi[H_ + j]; inn = gi[2*H_ + j];
    } else {
        ir = bih[j]; iz = bih[H_ + j]; inn = bih[2*H_ + j];
        const float* p = GI + (size_t)b * G3;
#pragma unroll
        for (int s = 0; s < KSPLIT; ++s) {
            ir += p[j]; iz += p[H_ + j]; inn += p[2*H_ + j];
            p += (size_t)B_ * G3;
        }
    }
    float hr = bhh[j], hz = bhh[H_ + j], hn = bhh[2*H_ + j];
    const float* q = GHp + (size_t)b * G3;
#pragma unroll
    for (int s = 0; s < KSPLIT; ++s) {
        hr += q[j]; hz += q[H_ + j]; hn += q[2*H_ + j];
        q += (size_t)B_ * G3;
    }
    const float v = gru_elem(ir, iz, inn, hr, hz, hn, h[idx]);
    h[idx] = v;
    split1(v, hh[idx], hl[idx]);
}

__global__ __launch_bounds__(256) void relu_combine(
    const float* __restrict__ Up, const float* __restrict__ bias,
    ushort_t* __restrict__ uh, ushort_t* __restrict__ ul)
{
    const int idx = blockIdx.x * 256 + threadIdx.x;
    const int j = idx & (H_ - 1);
    float v = bias[j];
#pragma unroll
    for (int s = 0; s < KSPLIT; ++s) v += Up[(size_t)s * B_ * H_ + idx];
    v = fmaxf(v, 0.f);
    split1(v, uh[idx], ul[idx]);
}

__global__ __launch_bounds__(256) void cat_eh_emb(
    const ushort_t* __restrict__ ehh, const ushort_t* __restrict__ ehl,
    const float* __restrict__ embed, const int* __restrict__ word,
    ushort_t* __restrict__ cath, ushort_t* __restrict__ catl)
{
    const int idx = blockIdx.x * 256 + threadIdx.x;
    const int b = idx >> 11;
    const int j = idx & (2*H_ - 1);
    if (j < H_) {
        cath[idx] = ehh[b * H_ + j];
        catl[idx] = ehl[b * H_ + j];
    } else {
        float v = embed[(size_t)word[b] * H_ + (j - H_)];
        split1(v, cath[idx], catl[idx]);
    }
}

// ---------------- init ----------------
__global__ __launch_bounds__(256) void init_state(
    float* __restrict__ eh, float* __restrict__ dh,
    ushort_t* __restrict__ dhh0, ushort_t* __restrict__ dhl0,
    int* __restrict__ word, float* __restrict__ out,
    float* __restrict__ ghs0, int* __restrict__ bar)
{
    const int idx = blockIdx.x * 256 + threadIdx.x;
    if (idx < B_*G3) ghs0[idx] = 0.f;          // ghs ring slot 0
    if (idx < B_*H_) {
        eh[idx] = 0.f; dh[idx] = 0.f;
        dhh0[idx] = 0; dhl0[idx] = 0;          // dh ring slot 0
    }
    if (idx < B_)   word[idx] = 1;
    if (idx < 21)   out[idx] = 0.f;
    if (idx < 512)  bar[idx] = 0;
}

// ---------------- log-softmax + argmax + loss over 2 logit partials ----------------
__global__ __launch_bounds__(256) void softmax_loss(
    const float* __restrict__ logp, const float* __restrict__ l2b,
    const int* __restrict__ target, int s, int* __restrict__ word,
    float* __restrict__ out)
{
    const int b = blockIdx.x;
    const int t = threadIdx.x;
    const float* p0 = logp + (size_t)b * VP;
    const float* p1 = p0 + (size_t)B_ * VP;
    __shared__ float sv[256];
    __shared__ int   si[256];
    __shared__ float ss[256];

    float best = -FLT_MAX; int bi = 0;
    for (int j = t; j < V_; j += 256) {
        float v = p0[j] + p1[j] + l2b[j];
        if (v > best) { best = v; bi = j; }
    }
    sv[t] = best; si[t] = bi;
    __syncthreads();
    for (int off = 128; off > 0; off >>= 1) {
        if (t < off) {
            float v2 = sv[t + off]; int i2 = si[t + off];
            if (v2 > sv[t] || (v2 == sv[t] && i2 < si[t])) { sv[t] = v2; si[t] = i2; }
        }
        __syncthreads();
    }
    const float m = sv[0];
    const int amax = si[0];

    float sum = 0.f;
    for (int j = t; j < V_; j += 256) sum += expf(p0[j] + p1[j] + l2b[j] - m);
    ss[t] = sum;
    __syncthreads();
    for (int off = 128; off > 0; off >>= 1) {
        if (t < off) ss[t] += ss[t + off];
        __syncthreads();
    }
    if (t == 0) {
        const float lse = m + logf(ss[0]);
        const int tgt = target[b * S_ + s];
        const float logit_t = p0[tgt] + p1[tgt] + l2b[tgt];
        atomicAdd(&out[0], -(logit_t - lse) * (1.0f / (float)B_));
        word[b] = amax;
        if (b == 0) out[1 + s]  = (float)amax;
        if (b == 1) out[11 + s] = (float)amax;
    }
}

// ---------------- host helpers ----------------
static inline void launch_x3(hipStream_t st,
    const ushort_t* Ah, const ushort_t* Al, int lda,
    const ushort_t* Bh, const ushort_t* Bl, int ldw,
    const float* bias, float* C, int M, int N, int K, int kchunks)
{
    dim3 grid(N/128, M/128, kchunks);
    gemm_x3<<<grid, 256, 0, st>>>(Ah, Al, lda, Bh, Bl, ldw, bias, C, M, N, K, kchunks,
                                  nullptr, nullptr, nullptr, nullptr, nullptr);
}

static inline void launch_x3_dual(hipStream_t st,
    const ushort_t* Ah, const ushort_t* Al,
    const ushort_t* Bh, const ushort_t* Bl, float* C,
    const ushort_t* A2h, const ushort_t* A2l,
    const ushort_t* B2h, const ushort_t* B2l, float* C2,
    int M, int N, int K, int kchunks)
{
    dim3 grid(N/128, M/128, 2*kchunks);
    gemm_x3<<<grid, 256, 0, st>>>(Ah, Al, H_, Bh, Bl, H_, nullptr, C, M, N, K, kchunks,
                                  A2h, A2l, B2h, B2l, C2);
}

extern "C" void kernel_launch(void* const* d_in, const int* in_sizes, int n_in,
                              void* d_out, int out_size, void* d_ws, size_t ws_size,
                              hipStream_t stream)
{
    const float* data    = (const float*)d_in[0];
    const int*   target  = (const int*)  d_in[2];
    const float* enc_Wih = (const float*)d_in[4];
    const float* enc_Whh = (const float*)d_in[5];
    const float* enc_bih = (const float*)d_in[6];
    const float* enc_bhh = (const float*)d_in[7];
    const float* dec_Wih = (const float*)d_in[8];
    const float* dec_Whh = (const float*)d_in[9];
    const float* dec_bih = (const float*)d_in[10];
    const float* dec_bhh = (const float*)d_in[11];
    const float* lin1_W  = (const float*)d_in[12];
    const float* lin1_b  = (const float*)d_in[13];
    const float* lin2_W  = (const float*)d_in[14];
    const float* lin2_b  = (const float*)d_in[15];
    const float* embed   = (const float*)d_in[16];
    float* out = (float*)d_out;

    float *gi, *eh, *dh, *logitsp, *ghp, *gi2p, *gh2p, *up;
    float *ghs_r, *gh2s_r, *gi2s_r, *us_r;
    ushort_t *Ah, *Al, *Bh, *Bl, *Whh_h, *Whh_l, *dWih_h, *dWih_l, *dWhh_h, *dWhh_l;
    ushort_t *l1h, *l1l, *l2h, *l2l, *uh, *ul, *cath, *catl;
    ushort_t *ehh_r, *ehl_r, *dhh_r, *dhl_r, *uh_r, *ul_r;
    int *word, *bar;
    hipGetSymbolAddress((void**)&gi,     HIP_SYMBOL(g_gi));
    hipGetSymbolAddress((void**)&Ah,     HIP_SYMBOL(g_Ah));
    hipGetSymbolAddress((void**)&Al,     HIP_SYMBOL(g_Al));
    hipGetSymbolAddress((void**)&Bh,     HIP_SYMBOL(g_Bh));
    hipGetSymbolAddress((void**)&Bl,     HIP_SYMBOL(g_Bl));
    hipGetSymbolAddress((void**)&Whh_h,  HIP_SYMBOL(g_Whh_h));
    hipGetSymbolAddress((void**)&Whh_l,  HIP_SYMBOL(g_Whh_l));
    hipGetSymbolAddress((void**)&dWih_h, HIP_SYMBOL(g_dWih_h));
    hipGetSymbolAddress((void**)&dWih_l, HIP_SYMBOL(g_dWih_l));
    hipGetSymbolAddress((void**)&dWhh_h, HIP_SYMBOL(g_dWhh_h));
    hipGetSymbolAddress((void**)&dWhh_l, HIP_SYMBOL(g_dWhh_l));
    hipGetSymbolAddress((void**)&l1h,    HIP_SYMBOL(g_l1h));
    hipGetSymbolAddress((void**)&l1l,    HIP_SYMBOL(g_l1l));
    hipGetSymbolAddress((void**)&l2h,    HIP_SYMBOL(g_l2h));
    hipGetSymbolAddress((void**)&l2l,    HIP_SYMBOL(g_l2l));
    hipGetSymbolAddress((void**)&ghp,    HIP_SYMBOL(g_ghp));
    hipGetSymbolAddress((void**)&gi2p,   HIP_SYMBOL(g_gi2p));
    hipGetSymbolAddress((void**)&gh2p,   HIP_SYMBOL(g_gh2p));
    hipGetSymbolAddress((void**)&up,     HIP_SYMBOL(g_up));
    hipGetSymbolAddress((void**)&ghs_r,  HIP_SYMBOL(g_ghs_r));
    hipGetSymbolAddress((void**)&gh2s_r, HIP_SYMBOL(g_gh2s_r));
    hipGetSymbolAddress((void**)&gi2s_r, HIP_SYMBOL(g_gi2s_r));
    hipGetSymbolAddress((void**)&us_r,   HIP_SYMBOL(g_us_r));
    hipGetSymbolAddress((void**)&eh,     HIP_SYMBOL(g_eh));
    hipGetSymbolAddress((void**)&dh,     HIP_SYMBOL(g_dh));
    hipGetSymbolAddress((void**)&ehh_r,  HIP_SYMBOL(g_ehh_r));
    hipGetSymbolAddress((void**)&ehl_r,  HIP_SYMBOL(g_ehl_r));
    hipGetSymbolAddress((void**)&dhh_r,  HIP_SYMBOL(g_dhh_r));
    hipGetSymbolAddress((void**)&dhl_r,  HIP_SYMBOL(g_dhl_r));
    hipGetSymbolAddress((void**)&uh_r,   HIP_SYMBOL(g_uh_r));
    hipGetSymbolAddress((void**)&ul_r,   HIP_SYMBOL(g_ul_r));
    hipGetSymbolAddress((void**)&uh,     HIP_SYMBOL(g_uh));
    hipGetSymbolAddress((void**)&ul,     HIP_SYMBOL(g_ul));
    hipGetSymbolAddress((void**)&cath,   HIP_SYMBOL(g_cath));
    hipGetSymbolAddress((void**)&catl,   HIP_SYMBOL(g_catl));
    hipGetSymbolAddress((void**)&logitsp,HIP_SYMBOL(g_logitsp));
    hipGetSymbolAddress((void**)&word,   HIP_SYMBOL(g_word));
    hipGetSymbolAddress((void**)&bar,    HIP_SYMBOL(g_bar));

    ushort_t* ehh_dec = ehh_r + (size_t)(T_-1)*B_*H_;
    ushort_t* ehl_dec = ehl_r + (size_t)(T_-1)*B_*H_;
    ushort_t* dhh_dec = dhh_r + (size_t)T_*B_*H_;
    ushort_t* dhl_dec = dhl_r + (size_t)T_*B_*H_;

    hipFuncSetAttribute((const void*)enc_persist,
                        hipFuncAttributeMaxDynamicSharedMemorySize, 131072);

    init_state<<<6144, 256, 0, stream>>>(eh, dh, dhh_r, dhl_r, word, out, ghs_r, bar);

    // bf16 hi/lo splits
    split_bf16<<<(B_*T_*D_/4 + 255)/256, 256, 0, stream>>>(data,    Ah, Al, B_*T_*D_/4);
    split_bf16<<<(G3*D_/4   + 255)/256, 256, 0, stream>>>(enc_Wih, Bh, Bl, G3*D_/4);
    split_bf16<<<(G3*H_/4   + 255)/256, 256, 0, stream>>>(enc_Whh, Whh_h, Whh_l, G3*H_/4);
    split_bf16<<<(G3*H_/4   + 255)/256, 256, 0, stream>>>(dec_Wih, dWih_h, dWih_l, G3*H_/4);
    split_bf16<<<(G3*H_/4   + 255)/256, 256, 0, stream>>>(dec_Whh, dWhh_h, dWhh_l, G3*H_/4);
    split_bf16<<<(H_*2*H_/4 + 255)/256, 256, 0, stream>>>(lin1_W,  l1h, l1l, H_*2*H_/4);
    split_bf16<<<(V_*H_/4   + 255)/256, 256, 0, stream>>>(lin2_W,  l2h, l2l, V_*H_/4);

    // gi[B*T][3H] = data @ enc_Wih^T + enc_bih
    launch_x3(stream, Ah, Al, D_, Bh, Bl, D_, enc_bih, gi, B_*T_, G3, D_, 1);

    // ---------------- encoder scan: ONE persistent launch ----------------
    enc_persist<<<NBLK, 512, 131072, stream>>>(
        gi, Whh_h, Whh_l, l1h, l1l, dWih_h, dWih_l, dWhh_h, dWhh_l,
        enc_bhh, lin1_b, dec_bih, dec_bhh,
        eh, dh,
        ehh_r, ehl_r, dhh_r, dhl_r, uh_r, ul_r,
        ghs_r, us_r, gi2s_r, gh2s_r, bar);

    // ---------------- decoder scan ----------------
    for (int s = 0; s < S_; ++s) {
        launch_x3(stream, ehh_dec, ehl_dec, H_, Whh_h, Whh_l, H_, nullptr, ghp, B_, G3, H_, KSPLIT);
        gru_update2<<<512, 256, 0, stream>>>(enc_bih, 0, 0, nullptr,
                                             ghp, enc_bhh, eh, ehh_dec, ehl_dec);
        cat_eh_emb<<<1024, 256, 0, stream>>>(ehh_dec, ehl_dec, embed, word, cath, catl);
        launch_x3(stream, cath, catl, 2*H_, l1h, l1l, 2*H_, nullptr, up, B_, H_, 2*H_, KSPLIT);
        relu_combine<<<512, 256, 0, stream>>>(up, lin1_b, uh, ul);
        launch_x3_dual(stream, uh, ul, dWih_h, dWih_l, gi2p,
                               dhh_dec, dhl_dec, dWhh_h, dWhh_l, gh2p, B_, G3, H_, KSPLIT);
        gru_update2<<<512, 256, 0, stream>>>(gi2p, 0, KSPLIT, dec_bih,
                                             gh2p, dec_bhh, dh, dhh_dec, dhl_dec);
        launch_x3(stream, dhh_dec, dhl_dec, H_, l2h, l2l, H_, nullptr, logitsp, B_, VP, H_, 2);
        softmax_loss<<<B_, 256, 0, stream>>>(logitsp, lin2_b, target, s, word, out);
    }
}